// Round 1
// baseline (13073.807 us; speedup 1.0000x reference)
//
#include <hip/hip_runtime.h>
#include <math.h>

#define NBATCH 64
#define EMBD   512
#define HIDD   1024
#define NVOC   32000
#define SEQL   64
#define NVT    500   // NVOC/64 vocab tiles

// ---- workspace layout (float offsets) ----
// h0     : 0        .. 65536      (64*1024)
// h1     : 65536    .. 131072
// x      : 131072   .. 163840     (64*512)
// gi     : 163840   .. 360448     (3072*64)  [n][b]
// gh     : 360448   .. 557056
// logits : 557056   .. 2605056    (64*32000) [b][v]
// pm     : 2605056  .. 2637056    (500*64)
// ps     : 2637056  .. 2669056
// total ~10.7 MB

__global__ __launch_bounds__(256) void k_init(const float* __restrict__ emb,
                                              float* __restrict__ ws) {
    int b = blockIdx.x, tid = threadIdx.x;
    float* h0 = ws;
    float* x  = ws + 131072;
    for (int j = tid; j < HIDD; j += 256) h0[b * HIDD + j] = 0.f;
    for (int k = tid; k < EMBD; k += 256) x[b * EMBD + k] = emb[k];
}

// Tiled GEMM core: acc[i][j] += sum_k W[n0+4*ty+i][k] * X[4*tx+j][k]
// K multiple of 16. 256 threads = 16x16 (tx,ty). 64-row W tile, all 64 X rows.
__device__ __forceinline__ void gemm_core(const float* __restrict__ W,
                                          const float* __restrict__ X,
                                          int K, int n0,
                                          float (*Ws)[68], float (*Xs)[68],
                                          float acc[4][4]) {
    int tid = threadIdx.x;
    int tx = tid & 15, ty = tid >> 4;
    int ldr = tid >> 2;          // 0..63: W row / X row to load
    int kq  = (tid & 3) * 4;     // 0,4,8,12

    for (int k0 = 0; k0 < K; k0 += 16) {
        float4 w4 = *(const float4*)(W + (size_t)(n0 + ldr) * K + k0 + kq);
        float4 x4 = *(const float4*)(X + (size_t)ldr * K + k0 + kq);
        __syncthreads();   // previous iteration's reads complete
        Ws[kq + 0][ldr] = w4.x; Ws[kq + 1][ldr] = w4.y;
        Ws[kq + 2][ldr] = w4.z; Ws[kq + 3][ldr] = w4.w;
        Xs[kq + 0][ldr] = x4.x; Xs[kq + 1][ldr] = x4.y;
        Xs[kq + 2][ldr] = x4.z; Xs[kq + 3][ldr] = x4.w;
        __syncthreads();
#pragma unroll
        for (int kk = 0; kk < 16; ++kk) {
            float4 a = *(const float4*)&Ws[kk][4 * ty];
            float4 b = *(const float4*)&Xs[kk][4 * tx];
            acc[0][0] += a.x * b.x; acc[0][1] += a.x * b.y;
            acc[0][2] += a.x * b.z; acc[0][3] += a.x * b.w;
            acc[1][0] += a.y * b.x; acc[1][1] += a.y * b.y;
            acc[1][2] += a.y * b.z; acc[1][3] += a.y * b.w;
            acc[2][0] += a.z * b.x; acc[2][1] += a.z * b.y;
            acc[2][2] += a.z * b.z; acc[2][3] += a.z * b.w;
            acc[3][0] += a.w * b.x; acc[3][1] += a.w * b.y;
            acc[3][2] += a.w * b.z; acc[3][3] += a.w * b.w;
        }
    }
}

// gates: out[n*64+b] = bias[n] + dot(W[n], X[b]); grid (48, 2)
__global__ __launch_bounds__(256) void k_gates(
    const float* __restrict__ w_ih, const float* __restrict__ b_ih,
    const float* __restrict__ x,    float* __restrict__ gi,
    const float* __restrict__ w_hh, const float* __restrict__ b_hh,
    const float* __restrict__ h,    float* __restrict__ gh) {
    __shared__ float Ws[16][68], Xs[16][68];
    const float* W; const float* X; const float* bias; float* out; int K;
    if (blockIdx.y == 0) { W = w_ih; X = x; bias = b_ih; out = gi; K = EMBD; }
    else                 { W = w_hh; X = h; bias = b_hh; out = gh; K = HIDD; }
    int n0 = blockIdx.x * 64;
    float acc[4][4] = {};
    gemm_core(W, X, K, n0, Ws, Xs, acc);
    int tid = threadIdx.x, tx = tid & 15, ty = tid >> 4;
#pragma unroll
    for (int i = 0; i < 4; ++i) {
        int n = n0 + 4 * ty + i;
        float bi = bias[n];
        float4 o = make_float4(acc[i][0] + bi, acc[i][1] + bi,
                               acc[i][2] + bi, acc[i][3] + bi);
        *(float4*)(out + n * 64 + 4 * tx) = o;
    }
}

// GRU elementwise: h_out[b][j]
__global__ __launch_bounds__(256) void k_gru(
    const float* __restrict__ gi, const float* __restrict__ gh,
    const float* __restrict__ h_in, float* __restrict__ h_out) {
    int tid = blockIdx.x * 256 + threadIdx.x;   // 65536 threads
    int b = tid & 63, j = tid >> 6;
    float ir = gi[j * 64 + b], iz = gi[(j + 1024) * 64 + b], in_ = gi[(j + 2048) * 64 + b];
    float hr = gh[j * 64 + b], hz = gh[(j + 1024) * 64 + b], hn = gh[(j + 2048) * 64 + b];
    float h = h_in[b * HIDD + j];
    float r = 1.f / (1.f + expf(-(ir + hr)));
    float z = 1.f / (1.f + expf(-(iz + hz)));
    float n = tanhf(in_ + r * hn);
    h_out[b * HIDD + j] = (1.f - z) * n + z * h;
}

// logits: logits[b][v] = dot(w_out[v], h[b]) + b_out[v], + per-block max/sumexp partials
__global__ __launch_bounds__(256) void k_logits(
    const float* __restrict__ w_out, const float* __restrict__ b_out,
    const float* __restrict__ h, float* __restrict__ logits,
    float* __restrict__ pm, float* __restrict__ ps) {
    __shared__ float Ws[16][68], Xs[16][68];
    __shared__ float red[16][64];
    __shared__ float sm[64];
    int v0 = blockIdx.x * 64;
    float acc[4][4] = {};
    gemm_core(w_out, h, HIDD, v0, Ws, Xs, acc);
    int tid = threadIdx.x, tx = tid & 15, ty = tid >> 4;
    float val[4][4];
#pragma unroll
    for (int i = 0; i < 4; ++i) {
        float bi = b_out[v0 + 4 * ty + i];
#pragma unroll
        for (int j = 0; j < 4; ++j) val[i][j] = acc[i][j] + bi;
    }
#pragma unroll
    for (int j = 0; j < 4; ++j) {
        float4 o = make_float4(val[0][j], val[1][j], val[2][j], val[3][j]);
        *(float4*)(logits + (size_t)(4 * tx + j) * NVOC + v0 + 4 * ty) = o;
    }
    // partial max per b over this block's 64 v
    __syncthreads();
#pragma unroll
    for (int j = 0; j < 4; ++j) {
        float mj = fmaxf(fmaxf(val[0][j], val[1][j]), fmaxf(val[2][j], val[3][j]));
        red[ty][4 * tx + j] = mj;
    }
    __syncthreads();
    if (tid < 64) {
        float m = red[0][tid];
#pragma unroll
        for (int r = 1; r < 16; ++r) m = fmaxf(m, red[r][tid]);
        sm[tid] = m;
    }
    __syncthreads();
#pragma unroll
    for (int j = 0; j < 4; ++j) {
        float mb = sm[4 * tx + j];
        float s = expf(val[0][j] - mb) + expf(val[1][j] - mb) +
                  expf(val[2][j] - mb) + expf(val[3][j] - mb);
        red[ty][4 * tx + j] = s;
    }
    __syncthreads();
    if (tid < 64) {
        float s = 0.f;
#pragma unroll
        for (int r = 0; r < 16; ++r) s += red[r][tid];
        pm[blockIdx.x * 64 + tid] = sm[tid];
        ps[blockIdx.x * 64 + tid] = s;
    }
}

// per-row: LSE combine, gumbel argmax, outputs, emb gather. grid 64
__global__ __launch_bounds__(256) void k_sample(
    const float* __restrict__ logits, const float* __restrict__ pm,
    const float* __restrict__ ps, const float* __restrict__ gumbel,
    const float* __restrict__ eps, const float* __restrict__ emb,
    float* __restrict__ xout, float* __restrict__ out, int t) {
    int b = blockIdx.x, tid = threadIdx.x;
    __shared__ float sred[256];
    __shared__ int sidx[256];

    float m = -INFINITY;
    for (int c = tid; c < NVT; c += 256) m = fmaxf(m, pm[c * 64 + b]);
    sred[tid] = m;
    __syncthreads();
    for (int s = 128; s > 0; s >>= 1) {
        if (tid < s) sred[tid] = fmaxf(sred[tid], sred[tid + s]);
        __syncthreads();
    }
    float M = sred[0];
    __syncthreads();
    float ss = 0.f;
    for (int c = tid; c < NVT; c += 256) ss += ps[c * 64 + b] * expf(pm[c * 64 + b] - M);
    sred[tid] = ss;
    __syncthreads();
    for (int s = 128; s > 0; s >>= 1) {
        if (tid < s) sred[tid] += sred[tid + s];
        __syncthreads();
    }
    float lse = M + logf(sred[0]);
    __syncthreads();

    bool draw = eps[t * 64 + b] <= 0.5f;
    const float LOGV = logf(32000.0f);
    const float* lrow = logits + (size_t)b * NVOC;
    const float* grow = gumbel + ((size_t)t * 64 + b) * NVOC;
    float bestv = -INFINITY; int besti = 0x7fffffff;
    for (int v = tid; v < NVOC; v += 256) {
        float u = grow[v];
        u = fminf(fmaxf(u, 1e-12f), 1.0f);
        float g = -logf(-logf(u));
        float base = draw ? -LOGV : (lrow[v] - lse);
        float sc = base + g;
        if (sc > bestv) { bestv = sc; besti = v; }
    }
    sred[tid] = bestv; sidx[tid] = besti;
    __syncthreads();
    for (int s = 128; s > 0; s >>= 1) {
        if (tid < s) {
            float ov = sred[tid + s]; int oi = sidx[tid + s];
            if (ov > sred[tid] || (ov == sred[tid] && oi < sidx[tid])) {
                sred[tid] = ov; sidx[tid] = oi;
            }
        }
        __syncthreads();
    }
    int sampled = sidx[0];
    if (tid == 0) {
        float lp = lrow[sampled] - lse;
        float bs = draw ? -LOGV : lp;
        float off = fminf(fmaxf(expf(bs), 0.001f), 1.0f);
        float corr = expf(lp) / off;
        out[b * SEQL + t] = (float)sampled;
        out[4096 + b * SEQL + t] = corr;
        out[8192 + b * SEQL + t] = lp;
    }
    const float* erow = emb + (size_t)sampled * EMBD;
    for (int k = tid; k < EMBD; k += 256) xout[b * EMBD + k] = erow[k];
}

extern "C" void kernel_launch(void* const* d_in, const int* in_sizes, int n_in,
                              void* d_out, int out_size, void* d_ws, size_t ws_size,
                              hipStream_t stream) {
    const float* emb   = (const float*)d_in[0];
    const float* w_ih  = (const float*)d_in[1];
    const float* w_hh  = (const float*)d_in[2];
    const float* b_ih  = (const float*)d_in[3];
    const float* b_hh  = (const float*)d_in[4];
    const float* w_out = (const float*)d_in[5];
    const float* b_out = (const float*)d_in[6];
    const float* gum   = (const float*)d_in[7];
    const float* eps   = (const float*)d_in[8];
    float* out = (float*)d_out;
    float* ws  = (float*)d_ws;

    float* h0     = ws;
    float* h1     = ws + 65536;
    float* x      = ws + 131072;
    float* gi     = ws + 163840;
    float* gh     = ws + 360448;
    float* logits = ws + 557056;
    float* pm     = ws + 2605056;
    float* psum   = ws + 2637056;

    k_init<<<64, 256, 0, stream>>>(emb, ws);
    for (int t = 0; t < SEQL; ++t) {
        float* hin  = (t & 1) ? h1 : h0;
        float* hout = (t & 1) ? h0 : h1;
        k_gates<<<dim3(48, 2), 256, 0, stream>>>(w_ih, b_ih, x, gi,
                                                 w_hh, b_hh, hin, gh);
        k_gru<<<256, 256, 0, stream>>>(gi, gh, hin, hout);
        k_logits<<<NVT, 256, 0, stream>>>(w_out, b_out, hout, logits, pm, psum);
        k_sample<<<64, 256, 0, stream>>>(logits, pm, psum, gum, eps, emb, x, out, t);
    }
}